// Round 6
// baseline (234.235 us; speedup 1.0000x reference)
//
#include <hip/hip_runtime.h>

#define NQ     12
#define NPARAM 240       // 12*4*5
#define BLOCK  512
#define NREG   8

// State layout: global index g[11:0]; qubit q sits at bit P = 11 - q.
//   g[2:0]   = register index r (st[8] per lane, 16 VGPRs)
//   g[8:3]   = lane index within wave (tid[5:0])
//   g[11:9]  = wave index (8 waves per block, tid[8:6]); tid = g[11:3]
// P < 3    -> register-class gate (static in-lane pairs)
// 3<=P<9   -> lane-class gate (DPP for xor1/2, shfl_xor for 4..32)
// P >= 9   -> block-class gate (LDS exchange via conflict-free buf[r][tid])
//
// R2-R5 lesson: the gfx950 allocator insists on a 64-VGPR / 8-waves-per-EU
// budget regardless of __launch_bounds__ / amdgpu_waves_per_eu, and spills
// to reach it. This structure needs only ~45 live VGPRs, so 64 is enough:
// no spill, and 8 waves/EU is genuinely achievable (4 blocks/CU x 8 waves).

template<int LM>
__device__ __forceinline__ float lxor(float v) {
    if constexpr (LM == 1) {        // quad_perm [1,0,3,2] = xor 1, VALU pipe
        return __int_as_float(__builtin_amdgcn_update_dpp(
            __float_as_int(v), __float_as_int(v), 0xB1, 0xF, 0xF, false));
    } else if constexpr (LM == 2) { // quad_perm [2,3,0,1] = xor 2, VALU pipe
        return __int_as_float(__builtin_amdgcn_update_dpp(
            __float_as_int(v), __float_as_int(v), 0x4E, 0xF, 0xF, false));
    } else {
        return __shfl_xor(v, LM, 64);
    }
}

__device__ __forceinline__ float2 cmulf(float2 a, float2 b) {
    return make_float2(a.x*b.x - a.y*b.y, a.x*b.y + a.y*b.x);
}

template<int P>
__device__ __forceinline__ void apply1q(float2* st, int tid,
                                        float2 (*buf)[BLOCK], const float* m) {
    float u00x=m[0],u00y=m[1],u01x=m[2],u01y=m[3];
    float u10x=m[4],u10y=m[5],u11x=m[6],u11y=m[7];
    if constexpr (P < 3) {
        #pragma unroll
        for (int r = 0; r < NREG; ++r) {
            if ((r >> P) & 1) continue;
            int r1 = r | (1 << P);
            float2 s0 = st[r], s1 = st[r1];
            st[r]  = make_float2(u00x*s0.x - u00y*s0.y + u01x*s1.x - u01y*s1.y,
                                 u00x*s0.y + u00y*s0.x + u01x*s1.y + u01y*s1.x);
            st[r1] = make_float2(u10x*s0.x - u10y*s0.y + u11x*s1.x - u11y*s1.y,
                                 u10x*s0.y + u10y*s0.x + u11x*s1.y + u11y*s1.x);
        }
    } else if constexpr (P < 9) {
        constexpr int LM = 1 << (P - 3);
        int bit = (tid >> (P - 3)) & 1;
        float uax = bit ? u11x : u00x, uay = bit ? u11y : u00y;
        float ubx = bit ? u10x : u01x, uby = bit ? u10y : u01y;
        #pragma unroll
        for (int r = 0; r < NREG; ++r) {
            float sx = st[r].x, sy = st[r].y;
            float ox = lxor<LM>(sx);
            float oy = lxor<LM>(sy);
            st[r] = make_float2(uax*sx - uay*sy + ubx*ox - uby*oy,
                                uax*sy + uay*sx + ubx*oy + uby*ox);
        }
    } else {
        constexpr int XM = 1 << (P - 3);       // 64/128/256 on tid
        int bit = (tid >> (P - 3)) & 1;
        float uax = bit ? u11x : u00x, uay = bit ? u11y : u00y;
        float ubx = bit ? u10x : u01x, uby = bit ? u10y : u01y;
        __syncthreads();                        // WAR vs prior buf reads
        #pragma unroll
        for (int r = 0; r < NREG; ++r) buf[r][tid] = st[r];
        __syncthreads();
        int pt = tid ^ XM;
        #pragma unroll
        for (int r = 0; r < NREG; ++r) {
            float2 o = buf[r][pt];
            float sx = st[r].x, sy = st[r].y;
            st[r] = make_float2(uax*sx - uay*sy + ubx*o.x - uby*o.y,
                                uax*sy + uay*sx + ubx*o.y + uby*o.x);
        }
    }
}

// CRX(ctrl bit PC, tgt bit PT): on ctrl=1 subspace apply RX: n = c*self - i*s*other
template<int PC, int PT>
__device__ __forceinline__ void applyCRX(float2* st, int tid,
                                         float2 (*buf)[BLOCK], const float* cs) {
    float c = cs[0], s = cs[1];
    if constexpr (PT < 3) {
        if constexpr (PC < 3) {
            #pragma unroll
            for (int r = 0; r < NREG; ++r) {
                if (!((r >> PC) & 1) || ((r >> PT) & 1)) continue;
                int r1 = r | (1 << PT);
                float2 s0 = st[r], s1 = st[r1];
                st[r]  = make_float2(c*s0.x + s*s1.y, c*s0.y - s*s1.x);
                st[r1] = make_float2(c*s1.x + s*s0.y, c*s1.y - s*s0.x);
            }
        } else {
            int apply = (tid >> (PC - 3)) & 1;
            float cc = apply ? c : 1.0f, ss = apply ? s : 0.0f;
            #pragma unroll
            for (int r = 0; r < NREG; ++r) {
                if ((r >> PT) & 1) continue;
                int r1 = r | (1 << PT);
                float2 s0 = st[r], s1 = st[r1];
                st[r]  = make_float2(cc*s0.x + ss*s1.y, cc*s0.y - ss*s1.x);
                st[r1] = make_float2(cc*s1.x + ss*s0.y, cc*s1.y - ss*s0.x);
            }
        }
    } else if constexpr (PT < 9) {
        constexpr int LM = 1 << (PT - 3);
        if constexpr (PC < 3) {
            #pragma unroll
            for (int r = 0; r < NREG; ++r) {
                if (!((r >> PC) & 1)) continue;
                float sx = st[r].x, sy = st[r].y;
                float ox = lxor<LM>(sx);
                float oy = lxor<LM>(sy);
                st[r] = make_float2(c*sx + s*oy, c*sy - s*ox);
            }
        } else {
            int apply = (tid >> (PC - 3)) & 1;
            float cc = apply ? c : 1.0f, ss = apply ? s : 0.0f;
            #pragma unroll
            for (int r = 0; r < NREG; ++r) {
                float sx = st[r].x, sy = st[r].y;
                float ox = lxor<LM>(sx);
                float oy = lxor<LM>(sy);
                st[r] = make_float2(cc*sx + ss*oy, cc*sy - ss*ox);
            }
        }
    } else {
        constexpr int XM = 1 << (PT - 3);
        if constexpr (PC < 3) {
            __syncthreads();
            #pragma unroll
            for (int r = 0; r < NREG; ++r)
                if ((r >> PC) & 1) buf[r][tid] = st[r];
            __syncthreads();
            int pt = tid ^ XM;
            #pragma unroll
            for (int r = 0; r < NREG; ++r) {
                if (!((r >> PC) & 1)) continue;
                float2 o = buf[r][pt];
                st[r] = make_float2(c*st[r].x + s*o.y, c*st[r].y - s*o.x);
            }
        } else {
            int apply = (tid >> (PC - 3)) & 1;
            float cc = apply ? c : 1.0f, ss = apply ? s : 0.0f;
            __syncthreads();
            #pragma unroll
            for (int r = 0; r < NREG; ++r) buf[r][tid] = st[r];
            __syncthreads();
            int pt = tid ^ XM;
            #pragma unroll
            for (int r = 0; r < NREG; ++r) {
                float2 o = buf[r][pt];
                st[r] = make_float2(cc*st[r].x + ss*o.y, cc*st[r].y - ss*o.x);
            }
        }
    }
}

template<int P>
__device__ __forceinline__ void expectq(const float2* st, int tid,
                                        float2 (*buf)[BLOCK],
                                        float& X, float& Y, float& Z) {
    float lx = 0.f, ly = 0.f, lz = 0.f;
    if constexpr (P < 3) {
        #pragma unroll
        for (int r = 0; r < NREG; ++r) {
            float2 a = st[r];
            float n = a.x*a.x + a.y*a.y;
            lz += ((r >> P) & 1) ? -n : n;
        }
        #pragma unroll
        for (int r = 0; r < NREG; ++r) {
            if ((r >> P) & 1) continue;
            int r1 = r | (1 << P);
            float2 s0 = st[r], s1 = st[r1];
            lx += s0.x*s1.x + s0.y*s1.y;
            ly += s0.x*s1.y - s0.y*s1.x;
        }
    } else if constexpr (P < 9) {
        constexpr int LM = 1 << (P - 3);
        int bit = (tid >> (P - 3)) & 1;
        float zs = bit ? -1.f : 1.f;
        float m  = bit ?  0.f : 1.f;
        #pragma unroll
        for (int r = 0; r < NREG; ++r) {
            float2 a = st[r];
            lz += zs * (a.x*a.x + a.y*a.y);
            float ox = lxor<LM>(a.x);
            float oy = lxor<LM>(a.y);
            lx += m * (a.x*ox + a.y*oy);
            ly += m * (a.x*oy - a.y*ox);
        }
    } else {
        constexpr int XM = 1 << (P - 3);
        int bit = (tid >> (P - 3)) & 1;
        float zs = bit ? -1.f : 1.f;
        float m  = bit ?  0.f : 1.f;
        __syncthreads();
        #pragma unroll
        for (int r = 0; r < NREG; ++r) buf[r][tid] = st[r];
        __syncthreads();
        int pt = tid ^ XM;
        #pragma unroll
        for (int r = 0; r < NREG; ++r) {
            float2 a = st[r];
            lz += zs * (a.x*a.x + a.y*a.y);
            float2 o = buf[r][pt];
            lx += m * (a.x*o.x + a.y*o.y);
            ly += m * (a.x*o.y - a.y*o.x);
        }
    }
    #pragma unroll
    for (int off = 32; off; off >>= 1) {
        lx += __shfl_xor(lx, off, 64);
        ly += __shfl_xor(ly, off, 64);
        lz += __shfl_xor(lz, off, 64);
    }
    X = 2.f*lx; Y = 2.f*ly; Z = lz;
}

__global__ __launch_bounds__(BLOCK)
void qfe_kernel(const float* __restrict__ params,
                const float* __restrict__ inputs,
                float* __restrict__ out) {
    const int b    = blockIdx.x;
    const int tid  = threadIdx.x;
    const int lane = tid & 63;
    const int w    = tid >> 6;

    __shared__ float2 buf[NREG][BLOCK];   // 32 KB exchange buffer, conflict-free
    __shared__ float  m1[4 * 12 * 8];     // fused (Rz*Ry*Rx [*RYembed]) matrices
    __shared__ float  mcrx[4 * 24 * 2];
    __shared__ float  redbuf[8][36];

    if (tid < 48) {
        int l = tid / 12, q = tid % 12;
        const float* pp = params + b * NPARAM + l * 60 + q * 3;
        float ax = pp[0]*0.5f, ay = pp[1]*0.5f, az = pp[2]*0.5f;
        float cx = cosf(ax), sx = sinf(ax);
        float cy = cosf(ay), sy = sinf(ay);
        float cz = cosf(az), sz = sinf(az);
        float2 a00 = make_float2( cy*cx,  sy*sx);
        float2 a01 = make_float2(-sy*cx, -cy*sx);
        float2 a10 = make_float2( sy*cx, -cy*sx);
        float2 a11 = make_float2( cy*cx, -sy*sx);
        float2 e0 = make_float2(cz, -sz);
        float2 e1 = make_float2(cz,  sz);
        float2 u00 = cmulf(e0, a00), u01 = cmulf(e0, a01);
        float2 u10 = cmulf(e1, a10), u11 = cmulf(e1, a11);
        if (l == 0) {
            // fold RY input embedding: U = (Rz Ry Rx) * RY(e)
            float e = inputs[b * NQ + q] * 0.5f;
            float ce = cosf(e), se = sinf(e);
            float2 v00 = make_float2(u00.x*ce + u01.x*se, u00.y*ce + u01.y*se);
            float2 v01 = make_float2(-u00.x*se + u01.x*ce, -u00.y*se + u01.y*ce);
            float2 v10 = make_float2(u10.x*ce + u11.x*se, u10.y*ce + u11.y*se);
            float2 v11 = make_float2(-u10.x*se + u11.x*ce, -u10.y*se + u11.y*ce);
            u00 = v00; u01 = v01; u10 = v10; u11 = v11;
        }
        float* m = &m1[(l * 12 + q) * 8];
        m[0]=u00.x; m[1]=u00.y; m[2]=u01.x; m[3]=u01.y;
        m[4]=u10.x; m[5]=u10.y; m[6]=u11.x; m[7]=u11.y;
    }
    if (tid < 96) {
        int l = tid / 24, k = tid % 24;
        float a = params[b * NPARAM + l * 60 + 36 + k] * 0.5f;
        mcrx[(l * 24 + k) * 2]     = cosf(a);
        mcrx[(l * 24 + k) * 2 + 1] = sinf(a);
    }
    __syncthreads();

    float2 st[NREG];
    #pragma unroll
    for (int r = 0; r < NREG; ++r) st[r] = make_float2(0.f, 0.f);
    if (tid == 0) st[0] = make_float2(1.f, 0.f);

#define APPLY1Q(q) apply1q<11 - (q)>(st, tid, buf, ml + (q) * 8);
// ring1 step j: ctrl q=j (PC=11-j), tgt q=(j+1)%12 (PT=11-((j+1)%12))
#define R1(j) applyCRX<11 - (j), (11 - (((j) + 1) % 12))>(st, tid, buf, cl + (j) * 2);
// ring2 step k: ctrl q=11-k (PC=k), tgt=(10-k)%12 (PT=11-((22-k)%12))
#define R2(k) applyCRX<(k), (11 - ((22 - (k)) % 12))>(st, tid, buf, cl + (12 + (k)) * 2);

    #pragma unroll 1
    for (int l = 0; l < 4; ++l) {
        const float* ml = m1 + l * 96;
        const float* cl = mcrx + l * 48;
        APPLY1Q(0)  APPLY1Q(1)  APPLY1Q(2)  APPLY1Q(3)
        APPLY1Q(4)  APPLY1Q(5)  APPLY1Q(6)  APPLY1Q(7)
        APPLY1Q(8)  APPLY1Q(9)  APPLY1Q(10) APPLY1Q(11)
        R1(0)  R1(1)  R1(2)  R1(3)  R1(4)  R1(5)
        R1(6)  R1(7)  R1(8)  R1(9)  R1(10) R1(11)
        R2(0)  R2(1)  R2(2)  R2(3)  R2(4)  R2(5)
        R2(6)  R2(7)  R2(8)  R2(9)  R2(10) R2(11)
    }

#define EXPECT(q) { float X, Y, Z; expectq<11 - (q)>(st, tid, buf, X, Y, Z); \
                    if (lane == 0) { redbuf[w][(q)] = X; redbuf[w][12 + (q)] = Y; redbuf[w][24 + (q)] = Z; } }
    EXPECT(0)  EXPECT(1)  EXPECT(2)  EXPECT(3)
    EXPECT(4)  EXPECT(5)  EXPECT(6)  EXPECT(7)
    EXPECT(8)  EXPECT(9)  EXPECT(10) EXPECT(11)
    __syncthreads();
    if (tid < 36) {
        float acc = 0.f;
        #pragma unroll
        for (int i = 0; i < 8; ++i) acc += redbuf[i][tid];
        out[b * 36 + tid] = acc;
    }
}

extern "C" void kernel_launch(void* const* d_in, const int* in_sizes, int n_in,
                              void* d_out, int out_size, void* d_ws, size_t ws_size,
                              hipStream_t stream) {
    const float* params = (const float*)d_in[0];   // (1024, 240) float32
    const float* inputs = (const float*)d_in[1];   // (1024, 12)  float32
    float* out = (float*)d_out;                    // (1024, 36)  float32
    qfe_kernel<<<1024, BLOCK, 0, stream>>>(params, inputs, out);
}

// Round 7
// 227.844 us; speedup vs baseline: 1.0281x; 1.0281x over previous
//
#include <hip/hip_runtime.h>

#define NQ     12
#define NPARAM 240       // 12*4*5
#define BLOCK  512
#define NREG   8

// Storage: thread tid (9 bits) x register r (3 bits). Storage position p:
//   p in [0,3)  -> register bit p of r          (VALU, pairs in-lane)
//   p in [3,9)  -> lane bit (p-3) of tid        (p=3,4: DPP quad_perm = VALU;
//                                                p>=5: ds_bpermute = LDS pipe)
//   p in [9,12) -> tid bit (p-3), cross-wave    (LDS exchange)
// Qubit q's basis bit is bit q of the 12-bit basis index B.
// QMAP[m][p] = qubit stored at position p under map m. Gates are applied only
// when their target qubit sits at p<5 (pure VALU); remaps (full LDS round
// trip, xor-swizzled) rotate qubits through the cheap positions.
// R6 lesson: __shfl_xor IS the LDS pipe (ds_bpermute) — R6 was LDS-bound.

constexpr int QMAP[5][12] = {
    { 0, 1, 2, 3, 4,  5, 6, 7, 8,  9,10,11},   // M0
    { 5, 6, 7, 8, 9,  0, 1, 2, 3,  4,10,11},   // M1
    {10,11, 0, 9, 8,  1, 2, 3, 4,  5, 6, 7},   // M2
    { 7, 6, 5, 4, 3,  8, 9,10,11,  0, 1, 2},   // M3
    { 2, 1, 0,11, 3,  4, 5, 6, 7,  8, 9,10},   // M4
};

constexpr int swz(int x) { return x ^ ((x >> 4) & 15) ^ ((x >> 8) & 15); }
constexpr int scat_r(int m, int r) {
    return (((r >> 0) & 1) << QMAP[m][0]) |
           (((r >> 1) & 1) << QMAP[m][1]) |
           (((r >> 2) & 1) << QMAP[m][2]);
}

template<int LM>
__device__ __forceinline__ float lxor(float v) {
    if constexpr (LM == 1) {        // quad_perm [1,0,3,2] = xor 1, VALU pipe
        return __int_as_float(__builtin_amdgcn_update_dpp(
            __float_as_int(v), __float_as_int(v), 0xB1, 0xF, 0xF, false));
    } else if constexpr (LM == 2) { // quad_perm [2,3,0,1] = xor 2, VALU pipe
        return __int_as_float(__builtin_amdgcn_update_dpp(
            __float_as_int(v), __float_as_int(v), 0x4E, 0xF, 0xF, false));
    } else {
        return __shfl_xor(v, LM, 64);
    }
}

__device__ __forceinline__ float2 cmulf(float2 a, float2 b) {
    return make_float2(a.x*b.x - a.y*b.y, a.x*b.y + a.y*b.x);
}

template<int MA, int MB>
__device__ __forceinline__ void remap(float2* st, int tid, float2* buf) {
    int sa = 0;
    #pragma unroll
    for (int p = 3; p < 12; ++p) sa |= ((tid >> (p - 3)) & 1) << QMAP[MA][p];
    sa = swz(sa);
    __syncthreads();                 // WAR vs previous buf readers
    #pragma unroll
    for (int r = 0; r < NREG; ++r) buf[sa ^ swz(scat_r(MA, r))] = st[r];
    int sb = 0;
    #pragma unroll
    for (int p = 3; p < 12; ++p) sb |= ((tid >> (p - 3)) & 1) << QMAP[MB][p];
    sb = swz(sb);
    __syncthreads();
    #pragma unroll
    for (int r = 0; r < NREG; ++r) st[r] = buf[sb ^ swz(scat_r(MB, r))];
}

// 1q gate at storage position P (only P<5 instantiated by the schedule)
template<int P>
__device__ __forceinline__ void apply1q(float2* st, int tid, const float* m) {
    float u00x=m[0],u00y=m[1],u01x=m[2],u01y=m[3];
    float u10x=m[4],u10y=m[5],u11x=m[6],u11y=m[7];
    if constexpr (P < 3) {
        #pragma unroll
        for (int r = 0; r < NREG; ++r) {
            if ((r >> P) & 1) continue;
            int r1 = r | (1 << P);
            float2 s0 = st[r], s1 = st[r1];
            st[r]  = make_float2(u00x*s0.x - u00y*s0.y + u01x*s1.x - u01y*s1.y,
                                 u00x*s0.y + u00y*s0.x + u01x*s1.y + u01y*s1.x);
            st[r1] = make_float2(u10x*s0.x - u10y*s0.y + u11x*s1.x - u11y*s1.y,
                                 u10x*s0.y + u10y*s0.x + u11x*s1.y + u11y*s1.x);
        }
    } else {
        constexpr int LM = 1 << (P - 3);
        int bit = (tid >> (P - 3)) & 1;
        float uax = bit ? u11x : u00x, uay = bit ? u11y : u00y;
        float ubx = bit ? u10x : u01x, uby = bit ? u10y : u01y;
        #pragma unroll
        for (int r = 0; r < NREG; ++r) {
            float sx = st[r].x, sy = st[r].y;
            float ox = lxor<LM>(sx);
            float oy = lxor<LM>(sy);
            st[r] = make_float2(uax*sx - uay*sy + ubx*ox - uby*oy,
                                uax*sy + uay*sx + ubx*oy + uby*ox);
        }
    }
}

// CRX: ctrl at pos PC (any), tgt at pos PT (<5 per schedule).
template<int PC, int PT>
__device__ __forceinline__ void applyCRX(float2* st, int tid, const float* cs) {
    float c = cs[0], s = cs[1];
    if constexpr (PT < 3) {
        if constexpr (PC < 3) {
            #pragma unroll
            for (int r = 0; r < NREG; ++r) {
                if (!((r >> PC) & 1) || ((r >> PT) & 1)) continue;
                int r1 = r | (1 << PT);
                float2 s0 = st[r], s1 = st[r1];
                st[r]  = make_float2(c*s0.x + s*s1.y, c*s0.y - s*s1.x);
                st[r1] = make_float2(c*s1.x + s*s0.y, c*s1.y - s*s0.x);
            }
        } else {
            int apply = (tid >> (PC - 3)) & 1;
            float cc = apply ? c : 1.0f, ss = apply ? s : 0.0f;
            #pragma unroll
            for (int r = 0; r < NREG; ++r) {
                if ((r >> PT) & 1) continue;
                int r1 = r | (1 << PT);
                float2 s0 = st[r], s1 = st[r1];
                st[r]  = make_float2(cc*s0.x + ss*s1.y, cc*s0.y - ss*s1.x);
                st[r1] = make_float2(cc*s1.x + ss*s0.y, cc*s1.y - ss*s0.x);
            }
        }
    } else {
        constexpr int LM = 1 << (PT - 3);
        if constexpr (PC < 3) {
            #pragma unroll
            for (int r = 0; r < NREG; ++r) {
                if (!((r >> PC) & 1)) continue;
                float sx = st[r].x, sy = st[r].y;
                float ox = lxor<LM>(sx);
                float oy = lxor<LM>(sy);
                st[r] = make_float2(c*sx + s*oy, c*sy - s*ox);
            }
        } else {
            int apply = (tid >> (PC - 3)) & 1;
            float cc = apply ? c : 1.0f, ss = apply ? s : 0.0f;
            #pragma unroll
            for (int r = 0; r < NREG; ++r) {
                float sx = st[r].x, sy = st[r].y;
                float ox = lxor<LM>(sx);
                float oy = lxor<LM>(sy);
                st[r] = make_float2(cc*sx + ss*oy, cc*sy - ss*ox);
            }
        }
    }
}

// Expectation for qubit at position P (under M0: qubit q is at position q).
template<int P>
__device__ __forceinline__ void expectq(const float2* st, int tid, float2* buf,
                                        float& X, float& Y, float& Z) {
    float lx = 0.f, ly = 0.f, lz = 0.f;
    if constexpr (P < 3) {
        #pragma unroll
        for (int r = 0; r < NREG; ++r) {
            float2 a = st[r];
            float n = a.x*a.x + a.y*a.y;
            lz += ((r >> P) & 1) ? -n : n;
        }
        #pragma unroll
        for (int r = 0; r < NREG; ++r) {
            if ((r >> P) & 1) continue;
            int r1 = r | (1 << P);
            float2 s0 = st[r], s1 = st[r1];
            lx += s0.x*s1.x + s0.y*s1.y;
            ly += s0.x*s1.y - s0.y*s1.x;
        }
    } else if constexpr (P < 9) {
        constexpr int LM = 1 << (P - 3);
        int bit = (tid >> (P - 3)) & 1;
        float zs = bit ? -1.f : 1.f;
        float m  = bit ?  0.f : 1.f;
        #pragma unroll
        for (int r = 0; r < NREG; ++r) {
            float2 a = st[r];
            lz += zs * (a.x*a.x + a.y*a.y);
            float ox = lxor<LM>(a.x);
            float oy = lxor<LM>(a.y);
            lx += m * (a.x*ox + a.y*oy);
            ly += m * (a.x*oy - a.y*ox);
        }
    } else {
        constexpr int XM = 1 << (P - 3);
        int bit = (tid >> (P - 3)) & 1;
        float zs = bit ? -1.f : 1.f;
        float m  = bit ?  0.f : 1.f;
        __syncthreads();
        #pragma unroll
        for (int r = 0; r < NREG; ++r) buf[r * BLOCK + tid] = st[r];
        __syncthreads();
        int pt = tid ^ XM;
        #pragma unroll
        for (int r = 0; r < NREG; ++r) {
            float2 a = st[r];
            lz += zs * (a.x*a.x + a.y*a.y);
            float2 o = buf[r * BLOCK + pt];
            lx += m * (a.x*o.x + a.y*o.y);
            ly += m * (a.x*o.y - a.y*o.x);
        }
    }
    #pragma unroll
    for (int off = 32; off; off >>= 1) {
        lx += __shfl_xor(lx, off, 64);
        ly += __shfl_xor(ly, off, 64);
        lz += __shfl_xor(lz, off, 64);
    }
    X = 2.f*lx; Y = 2.f*ly; Z = lz;
}

__global__ __launch_bounds__(BLOCK)
void qfe_kernel(const float* __restrict__ params,
                const float* __restrict__ inputs,
                float* __restrict__ out) {
    const int b    = blockIdx.x;
    const int tid  = threadIdx.x;
    const int lane = tid & 63;
    const int w    = tid >> 6;

    __shared__ float2 buf[NREG * BLOCK];  // 32 KB remap/exchange buffer
    __shared__ float  m1[4 * 12 * 8];     // fused (Rz*Ry*Rx [*RYembed]) matrices
    __shared__ float  mcrx[4 * 24 * 2];
    __shared__ float  redbuf[8][36];

    if (tid < 48) {
        int l = tid / 12, q = tid % 12;
        const float* pp = params + b * NPARAM + l * 60 + q * 3;
        float ax = pp[0]*0.5f, ay = pp[1]*0.5f, az = pp[2]*0.5f;
        float cx = cosf(ax), sx = sinf(ax);
        float cy = cosf(ay), sy = sinf(ay);
        float cz = cosf(az), sz = sinf(az);
        float2 a00 = make_float2( cy*cx,  sy*sx);
        float2 a01 = make_float2(-sy*cx, -cy*sx);
        float2 a10 = make_float2( sy*cx, -cy*sx);
        float2 a11 = make_float2( cy*cx, -sy*sx);
        float2 e0 = make_float2(cz, -sz);
        float2 e1 = make_float2(cz,  sz);
        float2 u00 = cmulf(e0, a00), u01 = cmulf(e0, a01);
        float2 u10 = cmulf(e1, a10), u11 = cmulf(e1, a11);
        if (l == 0) {
            // fold RY input embedding: U = (Rz Ry Rx) * RY(e)
            float e = inputs[b * NQ + q] * 0.5f;
            float ce = cosf(e), se = sinf(e);
            float2 v00 = make_float2(u00.x*ce + u01.x*se, u00.y*ce + u01.y*se);
            float2 v01 = make_float2(-u00.x*se + u01.x*ce, -u00.y*se + u01.y*ce);
            float2 v10 = make_float2(u10.x*ce + u11.x*se, u10.y*ce + u11.y*se);
            float2 v11 = make_float2(-u10.x*se + u11.x*ce, -u10.y*se + u11.y*ce);
            u00 = v00; u01 = v01; u10 = v10; u11 = v11;
        }
        float* m = &m1[(l * 12 + q) * 8];
        m[0]=u00.x; m[1]=u00.y; m[2]=u01.x; m[3]=u01.y;
        m[4]=u10.x; m[5]=u10.y; m[6]=u11.x; m[7]=u11.y;
    }
    if (tid < 96) {
        int l = tid / 24, k = tid % 24;
        float a = params[b * NPARAM + l * 60 + 36 + k] * 0.5f;
        mcrx[(l * 24 + k) * 2]     = cosf(a);
        mcrx[(l * 24 + k) * 2 + 1] = sinf(a);
    }
    __syncthreads();

    float2 st[NREG];
    #pragma unroll
    for (int r = 0; r < NREG; ++r) st[r] = make_float2(0.f, 0.f);
    if (tid == 0) st[0] = make_float2(1.f, 0.f);

// A1(q, pos): 1q fused gate on qubit q currently stored at `pos`
#define A1(q, pos) apply1q<pos>(st, tid, ml + (q) * 8);
// CX(pc, pt, idx): CRX with ctrl at pos pc, tgt at pos pt, mcrx slot idx
#define CX(pc, pt, idx) applyCRX<pc, pt>(st, tid, cl + (idx) * 2);

    // Schedule (ring order preserved; only commuting reorders):
    // ring1 j: CRX(j,(j+1)%12) -> idx j ; ring2 i=11..0: CRX(i,i-1) -> idx 12+(11-i)
    #pragma unroll 1
    for (int l = 0; l < 4; ++l) {
        const float* ml = m1 + l * 96;
        const float* cl = mcrx + l * 48;
        // M0: cheap {0,1,2,3,4}
        A1(0,0) A1(1,1) A1(2,2) A1(3,3) A1(4,4)
        CX(0,1, 0) CX(1,2, 1) CX(2,3, 2) CX(3,4, 3)
        remap<0,1>(st, tid, buf);
        // M1: cheap {5,6,7,8,9}; q4@9
        A1(5,0) A1(6,1) A1(7,2) A1(8,3) A1(9,4)
        CX(9,0, 4) CX(0,1, 5) CX(1,2, 6) CX(2,3, 7) CX(3,4, 8)
        remap<1,2>(st, tid, buf);
        // M2: cheap {10,11,0,9,8}: q10@0,q11@1,q0@2,q9@3,q8@4
        A1(10,0) A1(11,1)
        CX(3,0, 9) CX(0,1, 10) CX(1,2, 11)          // ring1 (9,10),(10,11),(11,0)
        CX(1,0, 12) CX(0,3, 13) CX(3,4, 14)          // ring2 (11,10),(10,9),(9,8)
        remap<2,3>(st, tid, buf);
        // M3: cheap {7,6,5,4,3}: q7@0,q6@1,q5@2,q4@3,q3@4; q8@5
        CX(5,0, 15) CX(0,1, 16) CX(1,2, 17) CX(2,3, 18) CX(3,4, 19)
        remap<3,4>(st, tid, buf);
        // M4: cheap {2,1,0,11,3}: q2@0,q1@1,q0@2,q11@3,q3@4
        CX(4,0, 20) CX(0,1, 21) CX(1,2, 22) CX(2,3, 23)
        remap<4,0>(st, tid, buf);
    }

    // Expectations under M0 (qubit q at position q)
#define EXPECT(q) { float X, Y, Z; expectq<q>(st, tid, buf, X, Y, Z); \
                    if (lane == 0) { redbuf[w][(q)] = X; redbuf[w][12 + (q)] = Y; redbuf[w][24 + (q)] = Z; } }
    EXPECT(0)  EXPECT(1)  EXPECT(2)  EXPECT(3)
    EXPECT(4)  EXPECT(5)  EXPECT(6)  EXPECT(7)
    EXPECT(8)  EXPECT(9)  EXPECT(10) EXPECT(11)
    __syncthreads();
    if (tid < 36) {
        float acc = 0.f;
        #pragma unroll
        for (int i = 0; i < 8; ++i) acc += redbuf[i][tid];
        out[b * 36 + tid] = acc;
    }
}

extern "C" void kernel_launch(void* const* d_in, const int* in_sizes, int n_in,
                              void* d_out, int out_size, void* d_ws, size_t ws_size,
                              hipStream_t stream) {
    const float* params = (const float*)d_in[0];   // (1024, 240) float32
    const float* inputs = (const float*)d_in[1];   // (1024, 12)  float32
    float* out = (float*)d_out;                    // (1024, 36)  float32
    qfe_kernel<<<1024, BLOCK, 0, stream>>>(params, inputs, out);
}

// Round 8
// 147.630 us; speedup vs baseline: 1.5866x; 1.5434x over previous
//
#include <hip/hip_runtime.h>

#define NQ     12
#define NPARAM 240       // 12*4*5
#define BLOCK  512
#define NREG   8

// Storage position p for a qubit:
//   p in [0,3)  -> register bit p of r (st[8]/lane)     : pure VALU
//   p in [3,5)  -> lane bit (p-3), DPP quad_perm        : pure VALU
//   p in [5,9)  -> lane bit (p-3), shfl (ds_bpermute)   : LDS pipe (avoid for gates)
//   p in [9,12) -> tid bit (p-3) = wave bit             : select-only for ctrl
// QMAP[m][p] = qubit at position p under map m. All gate TARGETS are scheduled
// at positions 0..4 (VALU); controls anywhere (select / split loop). Remaps
// (LDS round trip) rotate qubits through the cheap positions.
//
// Remap bank rule (R7 lesson): write side uses e = r*512+tid (R6-proven
// conflict-free). Read conflicts are free iff the qubits at OLD positions
// 3..6 (-> e[3:0]) sit at LANE positions (3..8) in the new map. All five
// transitions below satisfy this (checked per-transition).

constexpr int QMAP[5][12] = {
    // pos:   0   1   2   3   4    5   6   7   8    9  10  11
    /*M0*/ {  0,  1,  2,  3,  4,  10, 11,  9,  8,   5,  6,  7},
    /*M1*/ {  5,  6,  7,  8,  9,   3,  4, 10, 11,   0,  1,  2},
    /*M2*/ { 10, 11,  0,  9,  8,   3,  4,  5,  6,   1,  2,  7},
    /*M3*/ {  7,  6,  5,  4,  3,   9,  8, 10, 11,   0,  1,  2},
    /*M4*/ {  2,  1,  0, 11,  4,   3,  9,  8, 10,   5,  6,  7},
};

constexpr int posof(int m, int q) {
    for (int p = 0; p < 12; ++p) if (QMAP[m][p] == q) return p;
    return -1;
}
// linear buf index e = (r_old << 9) | tid_old : old pos p -> e bit
constexpr int ebit(int p) { return p < 3 ? 9 + p : p - 3; }
// compile-time read offset contribution of new register index r (MA -> MB)
constexpr int roff(int MA, int MB, int r) {
    int off = 0;
    for (int p = 0; p < 3; ++p)
        off |= ((r >> p) & 1) << ebit(posof(MA, QMAP[MB][p]));
    return off;
}

template<int MA, int MB>
__device__ __forceinline__ int rbase(int tid) {
    int base = 0;
    #pragma unroll
    for (int p = 3; p < 12; ++p)
        base |= ((tid >> (p - 3)) & 1) << ebit(posof(MA, QMAP[MB][p]));
    return base;
}

template<int MA, int MB>
__device__ __forceinline__ void remap(float2* st, int tid, float2* buf, int base) {
    __syncthreads();                       // WAR vs previous buf readers
    #pragma unroll
    for (int r = 0; r < NREG; ++r) buf[r * BLOCK + tid] = st[r];
    __syncthreads();
    #pragma unroll
    for (int r = 0; r < NREG; ++r) st[r] = buf[base + roff(MA, MB, r)];
}

template<int LM>
__device__ __forceinline__ float lxor(float v) {
    if constexpr (LM == 1) {        // quad_perm [1,0,3,2] = xor 1, VALU pipe
        return __int_as_float(__builtin_amdgcn_update_dpp(
            __float_as_int(v), __float_as_int(v), 0xB1, 0xF, 0xF, false));
    } else if constexpr (LM == 2) { // quad_perm [2,3,0,1] = xor 2, VALU pipe
        return __int_as_float(__builtin_amdgcn_update_dpp(
            __float_as_int(v), __float_as_int(v), 0x4E, 0xF, 0xF, false));
    } else {
        return __shfl_xor(v, LM, 64);
    }
}

__device__ __forceinline__ float2 cmulf(float2 a, float2 b) {
    return make_float2(a.x*b.x - a.y*b.y, a.x*b.y + a.y*b.x);
}

// plain 1q gate at position P (used only for U(q0) at pos 0)
template<int P>
__device__ __forceinline__ void apply1q(float2* st, int tid, const float* m) {
    float u00x=m[0],u00y=m[1],u01x=m[2],u01y=m[3];
    float u10x=m[4],u10y=m[5],u11x=m[6],u11y=m[7];
    if constexpr (P < 3) {
        #pragma unroll
        for (int r = 0; r < NREG; ++r) {
            if ((r >> P) & 1) continue;
            int r1 = r | (1 << P);
            float2 s0 = st[r], s1 = st[r1];
            st[r]  = make_float2(u00x*s0.x - u00y*s0.y + u01x*s1.x - u01y*s1.y,
                                 u00x*s0.y + u00y*s0.x + u01x*s1.y + u01y*s1.x);
            st[r1] = make_float2(u10x*s0.x - u10y*s0.y + u11x*s1.x - u11y*s1.y,
                                 u10x*s0.y + u10y*s0.x + u11x*s1.y + u11y*s1.x);
        }
    } else {
        constexpr int LM = 1 << (P - 3);
        int bit = (tid >> (P - 3)) & 1;
        float dx = bit ? u11x : u00x, dy = bit ? u11y : u00y;
        float ox = bit ? u10x : u01x, oy = bit ? u10y : u01y;
        #pragma unroll
        for (int r = 0; r < NREG; ++r) {
            float sx = st[r].x, sy = st[r].y;
            float px = lxor<LM>(sx), py = lxor<LM>(sy);
            st[r] = make_float2(dx*sx - dy*sy + ox*px - oy*py,
                                dx*sy + dy*sx + ox*py + oy*px);
        }
    }
}

// fused ring1 gate: ctrl at PC, tgt at PT. Applies A (ctrl=0) / B (ctrl=1),
// where A = U(tgt), B = RX(theta)*U(tgt). PT always < 5 by schedule.
template<int PC, int PT>
__device__ __forceinline__ void fgate(float2* st, int tid,
                                      const float* A, const float* B) {
    if constexpr (PT < 3) {
        if constexpr (PC < 3) {
            #pragma unroll
            for (int r = 0; r < NREG; ++r) {
                if ((r >> PT) & 1) continue;
                const float* M = ((r >> PC) & 1) ? B : A;   // compile-time
                float m00x=M[0],m00y=M[1],m01x=M[2],m01y=M[3];
                float m10x=M[4],m10y=M[5],m11x=M[6],m11y=M[7];
                int r1 = r | (1 << PT);
                float2 s0 = st[r], s1 = st[r1];
                st[r]  = make_float2(m00x*s0.x - m00y*s0.y + m01x*s1.x - m01y*s1.y,
                                     m00x*s0.y + m00y*s0.x + m01x*s1.y + m01y*s1.x);
                st[r1] = make_float2(m10x*s0.x - m10y*s0.y + m11x*s1.x - m11y*s1.y,
                                     m10x*s0.y + m10y*s0.x + m11x*s1.y + m11y*s1.x);
            }
        } else {
            int cbit = (tid >> (PC - 3)) & 1;
            float m00x = cbit ? B[0] : A[0], m00y = cbit ? B[1] : A[1];
            float m01x = cbit ? B[2] : A[2], m01y = cbit ? B[3] : A[3];
            float m10x = cbit ? B[4] : A[4], m10y = cbit ? B[5] : A[5];
            float m11x = cbit ? B[6] : A[6], m11y = cbit ? B[7] : A[7];
            #pragma unroll
            for (int r = 0; r < NREG; ++r) {
                if ((r >> PT) & 1) continue;
                int r1 = r | (1 << PT);
                float2 s0 = st[r], s1 = st[r1];
                st[r]  = make_float2(m00x*s0.x - m00y*s0.y + m01x*s1.x - m01y*s1.y,
                                     m00x*s0.y + m00y*s0.x + m01x*s1.y + m01y*s1.x);
                st[r1] = make_float2(m10x*s0.x - m10y*s0.y + m11x*s1.x - m11y*s1.y,
                                     m10x*s0.y + m10y*s0.x + m11x*s1.y + m11y*s1.x);
            }
        }
    } else {
        constexpr int LM = 1 << (PT - 3);
        int tbit = (tid >> (PT - 3)) & 1;
        float dAx = tbit ? A[6] : A[0], dAy = tbit ? A[7] : A[1];
        float oAx = tbit ? A[4] : A[2], oAy = tbit ? A[5] : A[3];
        float dBx = tbit ? B[6] : B[0], dBy = tbit ? B[7] : B[1];
        float oBx = tbit ? B[4] : B[2], oBy = tbit ? B[5] : B[3];
        if constexpr (PC < 3) {
            #pragma unroll
            for (int r = 0; r < NREG; ++r) {
                const bool uB = (r >> PC) & 1;               // compile-time
                float dx = uB ? dBx : dAx, dy = uB ? dBy : dAy;
                float ox = uB ? oBx : oAx, oy = uB ? oBy : oAy;
                float sx = st[r].x, sy = st[r].y;
                float px = lxor<LM>(sx), py = lxor<LM>(sy);
                st[r] = make_float2(dx*sx - dy*sy + ox*px - oy*py,
                                    dx*sy + dy*sx + ox*py + oy*px);
            }
        } else {
            int cbit = (tid >> (PC - 3)) & 1;
            float dx = cbit ? dBx : dAx, dy = cbit ? dBy : dAy;
            float ox = cbit ? oBx : oAx, oy = cbit ? oBy : oAy;
            #pragma unroll
            for (int r = 0; r < NREG; ++r) {
                float sx = st[r].x, sy = st[r].y;
                float px = lxor<LM>(sx), py = lxor<LM>(sy);
                st[r] = make_float2(dx*sx - dy*sy + ox*px - oy*py,
                                    dx*sy + dy*sx + ox*py + oy*px);
            }
        }
    }
}

// CRX(ctrl at PC, tgt at PT<5): on ctrl=1 apply RX: n = c*self - i*s*other
template<int PC, int PT>
__device__ __forceinline__ void applyCRX(float2* st, int tid, const float* cs) {
    float c = cs[0], s = cs[1];
    if constexpr (PT < 3) {
        if constexpr (PC < 3) {
            #pragma unroll
            for (int r = 0; r < NREG; ++r) {
                if (!((r >> PC) & 1) || ((r >> PT) & 1)) continue;
                int r1 = r | (1 << PT);
                float2 s0 = st[r], s1 = st[r1];
                st[r]  = make_float2(c*s0.x + s*s1.y, c*s0.y - s*s1.x);
                st[r1] = make_float2(c*s1.x + s*s0.y, c*s1.y - s*s0.x);
            }
        } else {
            int apply = (tid >> (PC - 3)) & 1;
            float cc = apply ? c : 1.0f, ss = apply ? s : 0.0f;
            #pragma unroll
            for (int r = 0; r < NREG; ++r) {
                if ((r >> PT) & 1) continue;
                int r1 = r | (1 << PT);
                float2 s0 = st[r], s1 = st[r1];
                st[r]  = make_float2(cc*s0.x + ss*s1.y, cc*s0.y - ss*s1.x);
                st[r1] = make_float2(cc*s1.x + ss*s0.y, cc*s1.y - ss*s0.x);
            }
        }
    } else {
        constexpr int LM = 1 << (PT - 3);
        if constexpr (PC < 3) {
            #pragma unroll
            for (int r = 0; r < NREG; ++r) {
                if (!((r >> PC) & 1)) continue;
                float sx = st[r].x, sy = st[r].y;
                float px = lxor<LM>(sx), py = lxor<LM>(sy);
                st[r] = make_float2(c*sx + s*py, c*sy - s*px);
            }
        } else {
            int apply = (tid >> (PC - 3)) & 1;
            float cc = apply ? c : 1.0f, ss = apply ? s : 0.0f;
            #pragma unroll
            for (int r = 0; r < NREG; ++r) {
                float sx = st[r].x, sy = st[r].y;
                float px = lxor<LM>(sx), py = lxor<LM>(sy);
                st[r] = make_float2(cc*sx + ss*py, cc*sy - ss*px);
            }
        }
    }
}

template<int P>
__device__ __forceinline__ void expectq(const float2* st, int tid, float2* buf,
                                        float& X, float& Y, float& Z) {
    float lx = 0.f, ly = 0.f, lz = 0.f;
    if constexpr (P < 3) {
        #pragma unroll
        for (int r = 0; r < NREG; ++r) {
            float2 a = st[r];
            float n = a.x*a.x + a.y*a.y;
            lz += ((r >> P) & 1) ? -n : n;
        }
        #pragma unroll
        for (int r = 0; r < NREG; ++r) {
            if ((r >> P) & 1) continue;
            int r1 = r | (1 << P);
            float2 s0 = st[r], s1 = st[r1];
            lx += s0.x*s1.x + s0.y*s1.y;
            ly += s0.x*s1.y - s0.y*s1.x;
        }
    } else if constexpr (P < 9) {
        constexpr int LM = 1 << (P - 3);
        int bit = (tid >> (P - 3)) & 1;
        float zs = bit ? -1.f : 1.f;
        float m  = bit ?  0.f : 1.f;
        #pragma unroll
        for (int r = 0; r < NREG; ++r) {
            float2 a = st[r];
            lz += zs * (a.x*a.x + a.y*a.y);
            float px = lxor<LM>(a.x), py = lxor<LM>(a.y);
            lx += m * (a.x*px + a.y*py);
            ly += m * (a.x*py - a.y*px);
        }
    } else {
        constexpr int XM = 1 << (P - 3);
        int bit = (tid >> (P - 3)) & 1;
        float zs = bit ? -1.f : 1.f;
        float m  = bit ?  0.f : 1.f;
        __syncthreads();
        #pragma unroll
        for (int r = 0; r < NREG; ++r) buf[r * BLOCK + tid] = st[r];
        __syncthreads();
        int pt = tid ^ XM;
        #pragma unroll
        for (int r = 0; r < NREG; ++r) {
            float2 a = st[r];
            lz += zs * (a.x*a.x + a.y*a.y);
            float2 o = buf[r * BLOCK + pt];
            lx += m * (a.x*o.x + a.y*o.y);
            ly += m * (a.x*o.y - a.y*o.x);
        }
    }
    #pragma unroll
    for (int off = 32; off; off >>= 1) {
        lx += __shfl_xor(lx, off, 64);
        ly += __shfl_xor(ly, off, 64);
        lz += __shfl_xor(lz, off, 64);
    }
    X = 2.f*lx; Y = 2.f*ly; Z = lz;
}

__global__ __launch_bounds__(BLOCK)
void qfe_kernel(const float* __restrict__ params,
                const float* __restrict__ inputs,
                float* __restrict__ out) {
    const int b    = blockIdx.x;
    const int tid  = threadIdx.x;
    const int lane = tid & 63;
    const int w    = tid >> 6;

    __shared__ float2 buf[NREG * BLOCK];   // 32 KB remap/exchange buffer
    __shared__ float  mA[4 * 12 * 8];      // U = Rz*Ry*Rx (*RYembed at l=0)
    __shared__ float  mB[4 * 11 * 8];      // B = RX(ring1_j) * U(j+1), j=0..10
    __shared__ float  mcrx[4 * 24 * 2];    // (cos,sin) ring1 j=0..11, ring2 12..23
    __shared__ float  redbuf[8][36];

    if (tid < 48) {
        int l = tid / 12, q = tid % 12;
        const float* pp = params + b * NPARAM + l * 60 + q * 3;
        float ax = pp[0]*0.5f, ay = pp[1]*0.5f, az = pp[2]*0.5f;
        float cx = cosf(ax), sx = sinf(ax);
        float cy = cosf(ay), sy = sinf(ay);
        float cz = cosf(az), sz = sinf(az);
        float2 a00 = make_float2( cy*cx,  sy*sx);
        float2 a01 = make_float2(-sy*cx, -cy*sx);
        float2 a10 = make_float2( sy*cx, -cy*sx);
        float2 a11 = make_float2( cy*cx, -sy*sx);
        float2 e0 = make_float2(cz, -sz);
        float2 e1 = make_float2(cz,  sz);
        float2 u00 = cmulf(e0, a00), u01 = cmulf(e0, a01);
        float2 u10 = cmulf(e1, a10), u11 = cmulf(e1, a11);
        if (l == 0) {   // fold RY input embedding
            float e = inputs[b * NQ + q] * 0.5f;
            float ce = cosf(e), se = sinf(e);
            float2 v00 = make_float2(u00.x*ce + u01.x*se, u00.y*ce + u01.y*se);
            float2 v01 = make_float2(-u00.x*se + u01.x*ce, -u00.y*se + u01.y*ce);
            float2 v10 = make_float2(u10.x*ce + u11.x*se, u10.y*ce + u11.y*se);
            float2 v11 = make_float2(-u10.x*se + u11.x*ce, -u10.y*se + u11.y*ce);
            u00 = v00; u01 = v01; u10 = v10; u11 = v11;
        }
        float* m = &mA[(l * 12 + q) * 8];
        m[0]=u00.x; m[1]=u00.y; m[2]=u01.x; m[3]=u01.y;
        m[4]=u10.x; m[5]=u10.y; m[6]=u11.x; m[7]=u11.y;
    }
    if (tid < 96) {
        int l = tid / 24, k = tid % 24;
        float a = params[b * NPARAM + l * 60 + 36 + k] * 0.5f;
        mcrx[(l * 24 + k) * 2]     = cosf(a);
        mcrx[(l * 24 + k) * 2 + 1] = sinf(a);
    }
    __syncthreads();
    if (tid < 44) {       // B(l,j) = RX(theta_ring1_j) * U(l, j+1)
        int l = tid / 11, j = tid % 11;
        const float* U = mA + (l * 12 + (j + 1)) * 8;
        float c = mcrx[(l * 24 + j) * 2], s = mcrx[(l * 24 + j) * 2 + 1];
        float* Bm = mB + (l * 11 + j) * 8;
        Bm[0] =  c*U[0] + s*U[5];
        Bm[1] =  c*U[1] - s*U[4];
        Bm[2] =  c*U[2] + s*U[7];
        Bm[3] =  c*U[3] - s*U[6];
        Bm[4] =  s*U[1] + c*U[4];
        Bm[5] = -s*U[0] + c*U[5];
        Bm[6] =  s*U[3] + c*U[6];
        Bm[7] = -s*U[2] + c*U[7];
    }
    __syncthreads();

    float2 st[NREG];
    #pragma unroll
    for (int r = 0; r < NREG; ++r) st[r] = make_float2(0.f, 0.f);
    if (tid == 0) st[0] = make_float2(1.f, 0.f);

    // remap read bases (depend only on tid) — hoisted out of the layer loop
    const int rb1 = rbase<0,1>(tid);
    const int rb2 = rbase<1,2>(tid);
    const int rb3 = rbase<2,3>(tid);
    const int rb4 = rbase<3,4>(tid);
    const int rb0 = rbase<4,0>(tid);

    #pragma unroll 1
    for (int l = 0; l < 4; ++l) {
        const float* ma = mA + l * 96;
        const float* mb = mB + l * 88;
        const float* cl = mcrx + l * 48;
        // --- M0: q0@0,q1@1,q2@2,q3@3,q4@4 ---
        apply1q<0>(st, tid, ma + 0 * 8);               // U(q0)
        fgate<0, 1>(st, tid, ma + 1 * 8, mb + 0 * 8);  // F(0,1)
        fgate<1, 2>(st, tid, ma + 2 * 8, mb + 1 * 8);  // F(1,2)
        fgate<2, 3>(st, tid, ma + 3 * 8, mb + 2 * 8);  // F(2,3)
        fgate<3, 4>(st, tid, ma + 4 * 8, mb + 3 * 8);  // F(3,4)
        remap<0, 1>(st, tid, buf, rb1);
        // --- M1: q5@0,q6@1,q7@2,q8@3,q9@4; q4@6 ---
        fgate<6, 0>(st, tid, ma + 5 * 8, mb + 4 * 8);  // F(4,5)
        fgate<0, 1>(st, tid, ma + 6 * 8, mb + 5 * 8);  // F(5,6)
        fgate<1, 2>(st, tid, ma + 7 * 8, mb + 6 * 8);  // F(6,7)
        fgate<2, 3>(st, tid, ma + 8 * 8, mb + 7 * 8);  // F(7,8)
        fgate<3, 4>(st, tid, ma + 9 * 8, mb + 8 * 8);  // F(8,9)
        remap<1, 2>(st, tid, buf, rb2);
        // --- M2: q10@0,q11@1,q0@2,q9@3,q8@4 ---
        fgate<3, 0>(st, tid, ma + 10 * 8, mb + 9 * 8);  // F(9,10)
        fgate<0, 1>(st, tid, ma + 11 * 8, mb + 10 * 8); // F(10,11)
        applyCRX<1, 2>(st, tid, cl + 11 * 2);           // CRX(11,0) plain
        applyCRX<1, 0>(st, tid, cl + 12 * 2);           // ring2 (11,10)
        applyCRX<0, 3>(st, tid, cl + 13 * 2);           // (10,9)
        applyCRX<3, 4>(st, tid, cl + 14 * 2);           // (9,8)
        remap<2, 3>(st, tid, buf, rb3);
        // --- M3: q7@0,q6@1,q5@2,q4@3,q3@4; q8@6 ---
        applyCRX<6, 0>(st, tid, cl + 15 * 2);           // (8,7)
        applyCRX<0, 1>(st, tid, cl + 16 * 2);           // (7,6)
        applyCRX<1, 2>(st, tid, cl + 17 * 2);           // (6,5)
        applyCRX<2, 3>(st, tid, cl + 18 * 2);           // (5,4)
        applyCRX<3, 4>(st, tid, cl + 19 * 2);           // (4,3)
        remap<3, 4>(st, tid, buf, rb4);
        // --- M4: q2@0,q1@1,q0@2,q11@3; q3@5 ---
        applyCRX<5, 0>(st, tid, cl + 20 * 2);           // (3,2)
        applyCRX<0, 1>(st, tid, cl + 21 * 2);           // (2,1)
        applyCRX<1, 2>(st, tid, cl + 22 * 2);           // (1,0)
        applyCRX<2, 3>(st, tid, cl + 23 * 2);           // (0,11)
        remap<4, 0>(st, tid, buf, rb0);
    }

    // Expectations under M0: qubit -> position
    // 0..4 -> 0..4, 5->9, 6->10, 7->11, 8->8, 9->7, 10->5, 11->6
#define EXPECT(q, P) { float X, Y, Z; expectq<P>(st, tid, buf, X, Y, Z); \
                       if (lane == 0) { redbuf[w][(q)] = X; redbuf[w][12 + (q)] = Y; redbuf[w][24 + (q)] = Z; } }
    EXPECT(0, 0)  EXPECT(1, 1)  EXPECT(2, 2)  EXPECT(3, 3)
    EXPECT(4, 4)  EXPECT(5, 9)  EXPECT(6, 10) EXPECT(7, 11)
    EXPECT(8, 8)  EXPECT(9, 7)  EXPECT(10, 5) EXPECT(11, 6)
    __syncthreads();
    if (tid < 36) {
        float acc = 0.f;
        #pragma unroll
        for (int i = 0; i < 8; ++i) acc += redbuf[i][tid];
        out[b * 36 + tid] = acc;
    }
}

extern "C" void kernel_launch(void* const* d_in, const int* in_sizes, int n_in,
                              void* d_out, int out_size, void* d_ws, size_t ws_size,
                              hipStream_t stream) {
    const float* params = (const float*)d_in[0];   // (1024, 240) float32
    const float* inputs = (const float*)d_in[1];   // (1024, 12)  float32
    float* out = (float*)d_out;                    // (1024, 36)  float32
    qfe_kernel<<<1024, BLOCK, 0, stream>>>(params, inputs, out);
}